// Round 1
// baseline (395.020 us; speedup 1.0000x reference)
//
#include <hip/hip_runtime.h>

// Problem constants (match reference)
#define C_BINS 9
#define H_IN 180
#define W_IN 240
#define IMG 640
#define NEV 250000
#define BATCH 8
#define NEG_SLOPE 0.1f
#define HW (H_IN * W_IN)                         // 43200
#define NPIX (2 * BATCH * HW)                    // 691,200 (b,p,y,x) pixels
#define NV (NPIX * C_BINS)                       // 6,220,800 voxels (24.9 MB)
#define TN 2048                                  // table intervals (TN+1 nodes over [-1,1])
#define ROWF (W_IN * C_BINS)                     // 2160 floats per transposed vox row

// workspace layout (bytes) — unchanged size vs previous version
#define WS_BMAX_OFF   0            // 8 x i32 (float bits; signed-max trick, no init needed)
#define WS_TABLE_OFF  128          // (TN+1) x f32
#define WS_VOX_OFF    65536        // NV x f32 (16B aligned)

// ---------------- kernel A: fused prep ----------------
// Phase A: zero vox (float4, grid-stride)
// Phase B: per-batch max of t -> signed atomicMax on float bits.
// Phase C: block b computes table node b (one of TN+1).
__global__ __launch_bounds__(128) void prep_kernel(
        const float* __restrict__ ev,
        const float* __restrict__ W1, const float* __restrict__ b1,
        const float* __restrict__ W2, const float* __restrict__ b2,
        const float* __restrict__ W3, const float* __restrict__ b3,
        int* __restrict__ bmax_i, float* __restrict__ table,
        float4* __restrict__ vox4) {
    int blk = blockIdx.x, tid = threadIdx.x;
    int gtid = blk * 128 + tid;
    int gstride = gridDim.x * 128;

    // A: zero voxel grid
    float4 z = make_float4(0.f, 0.f, 0.f, 0.f);
    for (int i = gtid; i < NV / 4; i += gstride) vox4[i] = z;

    // B: per-batch max of t (t>0 -> int ordering == float ordering)
    __shared__ int smax[BATCH];
    if (tid < BATCH) smax[tid] = 0;
    __syncthreads();
    for (int i = gtid; i < NEV; i += gstride) {
        float t = ev[i * 5 + 2];
        int b = (int)ev[i * 5 + 4];
        atomicMax(&smax[b], __float_as_int(t));
    }
    __syncthreads();
    if (tid < BATCH) atomicMax(&bmax_i[tid], smax[tid]);

    // C: table node `blk`
    __shared__ float h1s[100];
    __shared__ float red[128];
    float s = -1.f + 2.f * (float)blk / (float)TN;
    if (tid < 100) {
        float h = fmaf(s, W1[tid], b1[tid]);
        h1s[tid] = h > 0.f ? h : NEG_SLOPE * h;
    }
    __syncthreads();
    float acc = 0.f;
    if (tid < 100) {
        #pragma unroll 4
        for (int j = 0; j < 100; ++j) acc = fmaf(h1s[j], W2[j * 100 + tid], acc);
        acc += b2[tid];
        acc = acc > 0.f ? acc : NEG_SLOPE * acc;
        acc *= W3[tid];
    }
    red[tid] = tid < 100 ? acc : 0.f;
    __syncthreads();
    for (int off = 64; off > 0; off >>= 1) {
        if (tid < off) red[tid] += red[tid + off];
        __syncthreads();
    }
    if (tid == 0) table[blk] = red[0] + b3[0];
}

// ---------------- kernel B: scatter events (bin-innermost layout) + bars ----
// vox layout: [((b*2+p)*HW + y*W + x)*9 + bin] -> an event's 9 atomics hit
// 36 contiguous bytes (1-2 cache lines) instead of 9 lines 172.8 KB apart.
// Letterbox bars (59 MB of constant 114) are folded in here: the scatter is
// atomic-latency-bound, so its store BW is free.
__global__ __launch_bounds__(256) void scatter_kernel(const float* __restrict__ ev,
                               const int* __restrict__ bmax_i,
                               const float* __restrict__ table,
                               float* __restrict__ vox,
                               float4* __restrict__ out4) {
    int i = blockIdx.x * 256 + threadIdx.x;
    if (i < NEV) {
        float x = ev[i * 5 + 0];
        float y = ev[i * 5 + 1];
        float t = ev[i * 5 + 2];
        float p = ev[i * 5 + 3];
        int   b = (int)ev[i * 5 + 4];
        float tn = t / __int_as_float(bmax_i[b]);
        int pix = ((b * 2 + (int)p) * H_IN + (int)y) * W_IN + (int)x;
        pix = max(0, min(pix, NPIX - 1));
        int base = pix * C_BINS;
        float u0 = (tn + 1.f) * (0.5f * (float)TN);
        int k0 = (int)floorf(u0);
        float f = u0 - (float)k0;
        #pragma unroll
        for (int bin = 0; bin < C_BINS; ++bin) {
            int k = k0 - 128 * bin;              // 128 = (1/8)*(TN/2), exact
            float fb = f;
            if (k >= TN) { k = TN - 1; fb = 1.f; }   // s == 1.0 exactly (the max event)
            if (k < 0)   { k = 0;      fb = 0.f; }   // cannot happen (s > -1), safety
            float t0 = table[k], t1 = table[k + 1];
            float g = fmaf(t1 - t0, fb, t0);
            atomicAdd(&vox[base + bin], tn * g);
        }
    }
    // letterbox bars: 144 planes x 160 rows (0..79, 560..639) x 160 float4
    const float4 v114 = make_float4(114.f, 114.f, 114.f, 114.f);
    int nth = gridDim.x * 256;
    for (int j = i; j < 144 * 160 * 160; j += nth) {
        int plane = j / 25600;
        int rem = j - plane * 25600;
        int row = rem / 160;
        int col = rem - row * 160;
        if (row >= 80) row += 480;               // 80..159 -> 560..639
        out4[((size_t)plane * IMG + row) * 160 + col] = v114;
    }
}

// ---------------- kernel C: bilinear resize, 9 planes per block ----------
// Block = (b, p, 8-row output tile). Stages 5 transposed-vox rows (240 px x
// 9 bins = 43.2 KB LDS, contiguous float4 loads), computes all 9 output
// planes: interpolation weights amortized 9x, vox read exactly once.
__global__ __launch_bounds__(256) void out_kernel(const float* __restrict__ vox,
                                                  float* __restrict__ out) {
    __shared__ float sm[5 * ROWF];               // 43,200 B
    int blk = blockIdx.x;
    int b   = blk / 120;
    int rem = blk - b * 120;
    int p   = rem / 60;
    int yt  = rem - p * 60;
    int tid = threadIdx.x;
    int ry0 = yt * 8;                            // resized-content row of tile start
    float sy0 = fmaf((float)ry0 + 0.5f, 0.375f, -0.5f);
    int ybase = (int)floorf(sy0);
    const float* plane_t = vox + (size_t)(b * 2 + p) * HW * C_BINS;

    #pragma unroll
    for (int r = 0; r < 5; ++r) {
        int sr = min(max(ybase + r, 0), H_IN - 1);
        const float4* src = (const float4*)(plane_t + (size_t)sr * ROWF);
        float4* dstl = (float4*)(sm + r * ROWF);
        for (int c = tid; c < ROWF / 4; c += 256) dstl[c] = src[c];
    }
    __syncthreads();

    int PB = b * 18 + p * 9;
    for (int g = tid; g < 1280; g += 256) {
        int row = g / 160;
        int gx = g - row * 160;
        int ry = ry0 + row;
        float sy = fmaf((float)ry + 0.5f, 0.375f, -0.5f);
        int y0 = (int)floorf(sy);
        float wy = sy - (float)y0;
        const float* r0 = sm + (max(y0, 0) - ybase) * ROWF;
        const float* r1 = sm + (min(y0 + 1, H_IN - 1) - ybase) * ROWF;
        float res[C_BINS][4];
        #pragma unroll
        for (int q = 0; q < 4; ++q) {
            int ox = gx * 4 + q;
            float sx = fmaf((float)ox + 0.5f, 0.375f, -0.5f);
            int x0 = (int)floorf(sx);
            float wx = sx - (float)x0;
            int x1 = min(x0 + 1, W_IN - 1);
            x0 = max(x0, 0);
            int o0 = x0 * C_BINS, o1 = x1 * C_BINS;
            #pragma unroll
            for (int bin = 0; bin < C_BINS; ++bin) {
                float v00 = r0[o0 + bin], v01 = r0[o1 + bin];
                float v10 = r1[o0 + bin], v11 = r1[o1 + bin];
                float top = fmaf(v01 - v00, wx, v00);
                float bot = fmaf(v11 - v10, wx, v10);
                res[bin][q] = fmaf(bot - top, wy, top);
            }
        }
        int oy = 80 + ry;
        #pragma unroll
        for (int bin = 0; bin < C_BINS; ++bin) {
            float4* dst = (float4*)(out + ((size_t)(PB + bin) * IMG + oy) * IMG);
            dst[gx] = make_float4(res[bin][0], res[bin][1], res[bin][2], res[bin][3]);
        }
    }
}

extern "C" void kernel_launch(void* const* d_in, const int* in_sizes, int n_in,
                              void* d_out, int out_size, void* d_ws, size_t ws_size,
                              hipStream_t stream) {
    const float* ev = (const float*)d_in[0];
    const float* W1 = (const float*)d_in[1];
    const float* b1 = (const float*)d_in[2];
    const float* W2 = (const float*)d_in[3];
    const float* b2 = (const float*)d_in[4];
    const float* W3 = (const float*)d_in[5];
    const float* b3 = (const float*)d_in[6];
    float* out = (float*)d_out;

    char* ws = (char*)d_ws;
    int*    bmax_i = (int*)(ws + WS_BMAX_OFF);
    float*  table  = (float*)(ws + WS_TABLE_OFF);
    float*  vox    = (float*)(ws + WS_VOX_OFF);

    prep_kernel<<<TN + 1, 128, 0, stream>>>(ev, W1, b1, W2, b2, W3, b3,
                                            bmax_i, table, (float4*)vox);
    scatter_kernel<<<(NEV + 255) / 256, 256, 0, stream>>>(ev, bmax_i, table, vox,
                                                          (float4*)out);
    out_kernel<<<8 * 2 * 60, 256, 0, stream>>>(vox, out);
}

// Round 2
// 322.855 us; speedup vs baseline: 1.2235x; 1.2235x over previous
//
#include <hip/hip_runtime.h>

// Problem constants (match reference)
#define C_BINS 9
#define H_IN 180
#define W_IN 240
#define IMG 640
#define NEV 250000
#define BATCH 8
#define NEG_SLOPE 0.1f
#define HW (H_IN * W_IN)                         // 43200
#define NPIX (2 * BATCH * HW)                    // 691,200 (b,p,y,x) pixels
#define NV (NPIX * C_BINS)                       // 6,220,800 voxels (24.9 MB)
#define TN 2048                                  // table intervals (TN+1 nodes over [-1,1])
#define ROWF (W_IN * C_BINS)                     // 2160 floats per transposed vox row
#define NROW (2 * BATCH * H_IN)                  // 2880 (b,p,y) rows
#define CAP 512                                  // bucket capacity per row (mean 87)

// workspace layout (bytes)
#define WS_BMAX_OFF   0            // 8 x i32 (float bits; signed-max trick, no init needed)
#define WS_TABLE_OFF  128          // (TN+1) x f32 -> ends 8324
#define WS_CUR_OFF    16384        // NROW x i32, padded x16 (one counter per 64B line)
#define WS_BKT_OFF    262144       // NROW x CAP x float2 = 11.8 MB
#define WS_VOX_OFF    16777216     // NV x f32 (24.9 MB)

// ---------------- kernel A: fused prep ----------------
// Phase A: zero vox + row cursors. Phase B: per-batch max of t (signed
// atomicMax on float bits). Phase C: block b computes table node b.
__global__ __launch_bounds__(128) void prep_kernel(
        const float* __restrict__ ev,
        const float* __restrict__ W1, const float* __restrict__ b1,
        const float* __restrict__ W2, const float* __restrict__ b2,
        const float* __restrict__ W3, const float* __restrict__ b3,
        int* __restrict__ bmax_i, float* __restrict__ table,
        int* __restrict__ cursor, float4* __restrict__ vox4) {
    int blk = blockIdx.x, tid = threadIdx.x;
    int gtid = blk * 128 + tid;
    int gstride = gridDim.x * 128;

    // A: zero voxel grid + cursors
    float4 z = make_float4(0.f, 0.f, 0.f, 0.f);
    for (int i = gtid; i < NV / 4; i += gstride) vox4[i] = z;
    for (int i = gtid; i < NROW * 16; i += gstride) cursor[i] = 0;

    // B: per-batch max of t (t>0 -> int ordering == float ordering)
    __shared__ int smax[BATCH];
    if (tid < BATCH) smax[tid] = 0;
    __syncthreads();
    for (int i = gtid; i < NEV; i += gstride) {
        float t = ev[i * 5 + 2];
        int b = (int)ev[i * 5 + 4];
        atomicMax(&smax[b], __float_as_int(t));
    }
    __syncthreads();
    if (tid < BATCH) atomicMax(&bmax_i[tid], smax[tid]);

    // C: table node `blk`
    __shared__ float h1s[100];
    __shared__ float red[128];
    float s = -1.f + 2.f * (float)blk / (float)TN;
    if (tid < 100) {
        float h = fmaf(s, W1[tid], b1[tid]);
        h1s[tid] = h > 0.f ? h : NEG_SLOPE * h;
    }
    __syncthreads();
    float acc = 0.f;
    if (tid < 100) {
        #pragma unroll 4
        for (int j = 0; j < 100; ++j) acc = fmaf(h1s[j], W2[j * 100 + tid], acc);
        acc += b2[tid];
        acc = acc > 0.f ? acc : NEG_SLOPE * acc;
        acc *= W3[tid];
    }
    red[tid] = tid < 100 ? acc : 0.f;
    __syncthreads();
    for (int off = 64; off > 0; off >>= 1) {
        if (tid < off) red[tid] += red[tid + off];
        __syncthreads();
    }
    if (tid == 0) table[blk] = red[0] + b3[0];
}

// ---------------- kernel B: place events into row buckets + bars ----------
// One cursor atomic per event (250k, over 2880 line-padded counters) instead
// of 9 vox atomics per event. Payload = (t, x); b,p,y are implied by row.
// Overflow (pos >= CAP, statistically impossible at mean 87) falls back to
// direct global atomics into the zeroed vox -- accum later does vox += LDS,
// so overflow contributions are preserved.
__global__ __launch_bounds__(256) void place_kernel(const float* __restrict__ ev,
                               const int* __restrict__ bmax_i,
                               const float* __restrict__ table,
                               int* __restrict__ cursor,
                               float2* __restrict__ bucket,
                               float* __restrict__ vox,
                               float4* __restrict__ out4) {
    int i = blockIdx.x * 256 + threadIdx.x;
    if (i < NEV) {
        float x = ev[i * 5 + 0];
        float y = ev[i * 5 + 1];
        float t = ev[i * 5 + 2];
        float p = ev[i * 5 + 3];
        int   b = (int)ev[i * 5 + 4];
        int xi = min(max((int)x, 0), W_IN - 1);
        int row = (b * 2 + (int)p) * H_IN + (int)y;
        row = min(max(row, 0), NROW - 1);
        int pos = atomicAdd(&cursor[row * 16], 1);
        if (pos < CAP) {
            bucket[(size_t)row * CAP + pos] = make_float2(t, (float)xi);
        } else {
            float tn = t / __int_as_float(bmax_i[b]);
            float u0 = (tn + 1.f) * (0.5f * (float)TN);
            int k0 = (int)floorf(u0);
            float f = u0 - (float)k0;
            #pragma unroll
            for (int bin = 0; bin < C_BINS; ++bin) {
                int k = k0 - 128 * bin;
                float fb = f;
                if (k >= TN) { k = TN - 1; fb = 1.f; }
                if (k < 0)   { k = 0;      fb = 0.f; }
                float t0 = table[k], t1 = table[k + 1];
                float g = fmaf(t1 - t0, fb, t0);
                atomicAdd(&vox[((size_t)row * W_IN + xi) * C_BINS + bin], tn * g);
            }
        }
    }
    // letterbox bars: 144 planes x 160 rows (0..79, 560..639) x 160 float4
    const float4 v114 = make_float4(114.f, 114.f, 114.f, 114.f);
    int nth = gridDim.x * 256;
    for (int j = blockIdx.x * 256 + threadIdx.x; j < 144 * 160 * 160; j += nth) {
        int plane = j / 25600;
        int rem = j - plane * 25600;
        int row = rem / 160;
        int col = rem - row * 160;
        if (row >= 80) row += 480;               // 80..159 -> 560..639
        out4[((size_t)plane * IMG + row) * 160 + col] = v114;
    }
}

// ---------------- kernel C: per-row accumulate (LDS atomics, no global) ----
// One block per (b,p,y) row: zero 2160-float LDS row, add the row's ~87
// events via ds_add_f32, then vox_row += sm (RMW keeps overflow path exact).
__global__ __launch_bounds__(256) void accum_kernel(const float2* __restrict__ bucket,
                               const int* __restrict__ cursor,
                               const int* __restrict__ bmax_i,
                               const float* __restrict__ table,
                               float* __restrict__ vox) {
    __shared__ float sm[ROWF];
    int row = blockIdx.x;
    int tid = threadIdx.x;
    for (int c = tid; c < ROWF; c += 256) sm[c] = 0.f;
    int b = row / (2 * H_IN);
    float bm = __int_as_float(bmax_i[b]);
    int count = min(cursor[row * 16], CAP);
    __syncthreads();
    for (int e = tid; e < count; e += 256) {
        float2 pay = bucket[(size_t)row * CAP + e];
        float tn = pay.x / bm;
        int xi = (int)pay.y;
        float u0 = (tn + 1.f) * (0.5f * (float)TN);
        int k0 = (int)floorf(u0);
        float f = u0 - (float)k0;
        #pragma unroll
        for (int bin = 0; bin < C_BINS; ++bin) {
            int k = k0 - 128 * bin;              // 128 = (1/8)*(TN/2), exact
            float fb = f;
            if (k >= TN) { k = TN - 1; fb = 1.f; }   // s == 1.0 exactly (the max event)
            if (k < 0)   { k = 0;      fb = 0.f; }   // cannot happen (s > -1), safety
            float t0 = table[k], t1 = table[k + 1];
            float g = fmaf(t1 - t0, fb, t0);
            atomicAdd(&sm[xi * C_BINS + bin], tn * g);
        }
    }
    __syncthreads();
    float4* vr4 = (float4*)(vox + (size_t)row * ROWF);
    const float4* sm4 = (const float4*)sm;
    for (int c = tid; c < ROWF / 4; c += 256) {
        float4 v = vr4[c];
        float4 s4 = sm4[c];
        v.x += s4.x; v.y += s4.y; v.z += s4.z; v.w += s4.w;
        vr4[c] = v;
    }
}

// ---------------- kernel D: bilinear resize, 9 planes per block ----------
__global__ __launch_bounds__(256) void out_kernel(const float* __restrict__ vox,
                                                  float* __restrict__ out) {
    __shared__ float sm[5 * ROWF];               // 43,200 B
    int blk = blockIdx.x;
    int b   = blk / 120;
    int rem = blk - b * 120;
    int p   = rem / 60;
    int yt  = rem - p * 60;
    int tid = threadIdx.x;
    int ry0 = yt * 8;                            // resized-content row of tile start
    float sy0 = fmaf((float)ry0 + 0.5f, 0.375f, -0.5f);
    int ybase = (int)floorf(sy0);
    const float* plane_t = vox + (size_t)(b * 2 + p) * HW * C_BINS;

    #pragma unroll
    for (int r = 0; r < 5; ++r) {
        int sr = min(max(ybase + r, 0), H_IN - 1);
        const float4* src = (const float4*)(plane_t + (size_t)sr * ROWF);
        float4* dstl = (float4*)(sm + r * ROWF);
        for (int c = tid; c < ROWF / 4; c += 256) dstl[c] = src[c];
    }
    __syncthreads();

    int PB = b * 18 + p * 9;
    for (int g = tid; g < 1280; g += 256) {
        int row = g / 160;
        int gx = g - row * 160;
        int ry = ry0 + row;
        float sy = fmaf((float)ry + 0.5f, 0.375f, -0.5f);
        int y0 = (int)floorf(sy);
        float wy = sy - (float)y0;
        const float* r0 = sm + (max(y0, 0) - ybase) * ROWF;
        const float* r1 = sm + (min(y0 + 1, H_IN - 1) - ybase) * ROWF;
        float res[C_BINS][4];
        #pragma unroll
        for (int q = 0; q < 4; ++q) {
            int ox = gx * 4 + q;
            float sx = fmaf((float)ox + 0.5f, 0.375f, -0.5f);
            int x0 = (int)floorf(sx);
            float wx = sx - (float)x0;
            int x1 = min(x0 + 1, W_IN - 1);
            x0 = max(x0, 0);
            int o0 = x0 * C_BINS, o1 = x1 * C_BINS;
            #pragma unroll
            for (int bin = 0; bin < C_BINS; ++bin) {
                float v00 = r0[o0 + bin], v01 = r0[o1 + bin];
                float v10 = r1[o0 + bin], v11 = r1[o1 + bin];
                float top = fmaf(v01 - v00, wx, v00);
                float bot = fmaf(v11 - v10, wx, v10);
                res[bin][q] = fmaf(bot - top, wy, top);
            }
        }
        int oy = 80 + ry;
        #pragma unroll
        for (int bin = 0; bin < C_BINS; ++bin) {
            float4* dst = (float4*)(out + ((size_t)(PB + bin) * IMG + oy) * IMG);
            dst[gx] = make_float4(res[bin][0], res[bin][1], res[bin][2], res[bin][3]);
        }
    }
}

extern "C" void kernel_launch(void* const* d_in, const int* in_sizes, int n_in,
                              void* d_out, int out_size, void* d_ws, size_t ws_size,
                              hipStream_t stream) {
    const float* ev = (const float*)d_in[0];
    const float* W1 = (const float*)d_in[1];
    const float* b1 = (const float*)d_in[2];
    const float* W2 = (const float*)d_in[3];
    const float* b2 = (const float*)d_in[4];
    const float* W3 = (const float*)d_in[5];
    const float* b3 = (const float*)d_in[6];
    float* out = (float*)d_out;

    char* ws = (char*)d_ws;
    int*    bmax_i = (int*)(ws + WS_BMAX_OFF);
    float*  table  = (float*)(ws + WS_TABLE_OFF);
    int*    cursor = (int*)(ws + WS_CUR_OFF);
    float2* bucket = (float2*)(ws + WS_BKT_OFF);
    float*  vox    = (float*)(ws + WS_VOX_OFF);

    prep_kernel<<<TN + 1, 128, 0, stream>>>(ev, W1, b1, W2, b2, W3, b3,
                                            bmax_i, table, cursor, (float4*)vox);
    place_kernel<<<(NEV + 255) / 256, 256, 0, stream>>>(ev, bmax_i, table, cursor,
                                                        bucket, vox, (float4*)out);
    accum_kernel<<<NROW, 256, 0, stream>>>(bucket, cursor, bmax_i, table, vox);
    out_kernel<<<8 * 2 * 60, 256, 0, stream>>>(vox, out);
}

// Round 3
// 300.765 us; speedup vs baseline: 1.3134x; 1.0734x over previous
//
#include <hip/hip_runtime.h>

// Problem constants (match reference)
#define C_BINS 9
#define H_IN 180
#define W_IN 240
#define IMG 640
#define NEV 250000
#define BATCH 8
#define NEG_SLOPE 0.1f
#define HW (H_IN * W_IN)                         // 43200
#define TN 2048                                  // table intervals (TN+1 nodes over [-1,1])
#define ROWF (W_IN * C_BINS)                     // 2160 floats per accumulated row
#define NROW (2 * BATCH * H_IN)                  // 2880 (b,p,y) rows
#define CAP 512                                  // bucket capacity per row (mean 87, ~45 sigma margin)
#define OVF_CAP 4096                             // spill list capacity (expected count: 0)

// workspace layout (bytes)
#define WS_BMAX_OFF   0            // 8 x i32 (float bits; signed-max trick, no init needed)
#define WS_OVFC_OFF   64           // 1 x i32 spill cursor
#define WS_TABLE_OFF  128          // (TN+1) x f32 -> ends 8324
#define WS_CUR_OFF    16384        // NROW x i32, padded x16 (one counter per 64B line)
#define WS_BKT_OFF    262144       // NROW x CAP x float2 = 11.8 MB
#define WS_OVF_OFF    12582912     // OVF_CAP x float4 = 64 KB

// ---------------- kernel A: prep (no event access) ----------------
// Zero row cursors + spill cursor; block b computes value-table node b.
__global__ __launch_bounds__(128) void prep_kernel(
        const float* __restrict__ W1, const float* __restrict__ b1,
        const float* __restrict__ W2, const float* __restrict__ b2,
        const float* __restrict__ W3, const float* __restrict__ b3,
        float* __restrict__ table, int* __restrict__ cursor,
        int* __restrict__ ovfc) {
    int blk = blockIdx.x, tid = threadIdx.x;
    int gtid = blk * 128 + tid;
    int gstride = gridDim.x * 128;
    for (int i = gtid; i < NROW * 16; i += gstride) cursor[i] = 0;
    if (gtid == 0) *ovfc = 0;

    // table node `blk`: two LeakyReLU layers + final linear, at s = -1 + 2*blk/TN
    __shared__ float h1s[100];
    __shared__ float red[128];
    float s = -1.f + 2.f * (float)blk / (float)TN;
    if (tid < 100) {
        float h = fmaf(s, W1[tid], b1[tid]);
        h1s[tid] = h > 0.f ? h : NEG_SLOPE * h;
    }
    __syncthreads();
    float acc = 0.f;
    if (tid < 100) {
        #pragma unroll 4
        for (int j = 0; j < 100; ++j) acc = fmaf(h1s[j], W2[j * 100 + tid], acc);
        acc += b2[tid];
        acc = acc > 0.f ? acc : NEG_SLOPE * acc;
        acc *= W3[tid];
    }
    red[tid] = tid < 100 ? acc : 0.f;
    __syncthreads();
    for (int off = 64; off > 0; off >>= 1) {
        if (tid < off) red[tid] += red[tid + off];
        __syncthreads();
    }
    if (tid == 0) table[blk] = red[0] + b3[0];
}

// ---------------- kernel B: place events into row buckets + batch max ------
// One cursor atomic per event (over 2880 line-padded counters). Payload =
// (raw t, x); b,p,y implied by row. bmax fused here (reuses the event read).
// Overflow (pos >= CAP, ~45 sigma out) goes to a tiny spill list that the
// fused kernel scans -- correctness never depends on CAP.
__global__ __launch_bounds__(256) void place_kernel(const float* __restrict__ ev,
                               int* __restrict__ cursor,
                               float2* __restrict__ bucket,
                               int* __restrict__ bmax_i,
                               int* __restrict__ ovfc,
                               float4* __restrict__ ovf) {
    int i = blockIdx.x * 256 + threadIdx.x;
    int tid = threadIdx.x;
    __shared__ int smax[BATCH];
    if (tid < BATCH) smax[tid] = 0;
    __syncthreads();
    if (i < NEV) {
        float x = ev[i * 5 + 0];
        float y = ev[i * 5 + 1];
        float t = ev[i * 5 + 2];
        float p = ev[i * 5 + 3];
        int   b = (int)ev[i * 5 + 4];
        atomicMax(&smax[b & (BATCH - 1)], __float_as_int(t));
        int xi = min(max((int)x, 0), W_IN - 1);
        int row = (b * 2 + (int)p) * H_IN + (int)y;
        row = min(max(row, 0), NROW - 1);
        int pos = atomicAdd(&cursor[row * 16], 1);
        if (pos < CAP) {
            bucket[(size_t)row * CAP + pos] = make_float2(t, (float)xi);
        } else {
            int opos = atomicAdd(ovfc, 1);
            if (opos < OVF_CAP)
                ovf[opos] = make_float4(t, (float)xi, (float)row, 0.f);
        }
    }
    __syncthreads();
    if (tid < BATCH) atomicMax(&bmax_i[tid], smax[tid]);  // poison is negative -> ok
}

// ---------------- kernel C: fused accumulate + bilinear resize + bars ------
// Content block = (b, p, 8-output-row tile): zero 5x2160-float LDS, pull the
// 5 needed source rows' events from buckets (ds_add_f32, ~435 events), then
// interpolate all 9 bin-planes straight from LDS. The 24.9 MB vox
// intermediate never exists (saves ~116 MB of HBM traffic + one dispatch).
// Blocks 960..1247 write the constant-114 letterbox bars.
__global__ __launch_bounds__(256) void fused_kernel(const float2* __restrict__ bucket,
                               const int* __restrict__ cursor,
                               const int* __restrict__ bmax_i,
                               const float* __restrict__ table,
                               const float4* __restrict__ ovf,
                               const int* __restrict__ ovfc,
                               float* __restrict__ out) {
    __shared__ float sm[5 * ROWF];               // 43,200 B -> 3 blocks/CU
    int blk = blockIdx.x;
    int tid = threadIdx.x;

    if (blk >= 960) {                            // letterbox bars
        const float4 v114 = make_float4(114.f, 114.f, 114.f, 114.f);
        float4* out4 = (float4*)out;
        int j0 = (blk - 960) * 12800 + tid;      // 288 blocks x 12800 float4
        for (int j = j0; j < (blk - 960 + 1) * 12800; j += 256) {
            int plane = j / 25600;
            int rem = j - plane * 25600;
            int row = rem / 160;
            int col = rem - row * 160;
            if (row >= 80) row += 480;           // 80..159 -> 560..639
            out4[((size_t)plane * IMG + row) * 160 + col] = v114;
        }
        return;
    }

    int b   = blk / 120;
    int rem = blk - b * 120;
    int p   = rem / 60;
    int yt  = rem - p * 60;
    int ry0 = yt * 8;                            // resized-content row of tile start
    float sy0 = fmaf((float)ry0 + 0.5f, 0.375f, -0.5f);
    int ybase = (int)floorf(sy0);
    int rowbase = (b * 2 + p) * H_IN;
    float bm = __int_as_float(bmax_i[b]);

    for (int c = tid; c < 5 * ROWF; c += 256) sm[c] = 0.f;
    __syncthreads();

    // accumulate the 5 source rows this tile needs
    #pragma unroll
    for (int r = 0; r < 5; ++r) {
        int sr = min(max(ybase + r, 0), H_IN - 1);
        int row = rowbase + sr;
        int count = min(cursor[row * 16], CAP);
        for (int e = tid; e < count; e += 256) {
            float2 pay = bucket[(size_t)row * CAP + e];
            float tn = pay.x / bm;
            int xi = (int)pay.y;
            float u0 = (tn + 1.f) * (0.5f * (float)TN);
            int k0 = (int)floorf(u0);
            float f = u0 - (float)k0;
            #pragma unroll
            for (int bin = 0; bin < C_BINS; ++bin) {
                int k = k0 - 128 * bin;          // 128 = (1/8)*(TN/2), exact
                float fb = f;
                if (k >= TN) { k = TN - 1; fb = 1.f; }   // s == 1.0 (the max event)
                if (k < 0)   { k = 0;      fb = 0.f; }   // safety
                float t0 = table[k], t1 = table[k + 1];
                float g = fmaf(t1 - t0, fb, t0);
                atomicAdd(&sm[r * ROWF + xi * C_BINS + bin], tn * g);
            }
        }
    }
    // spill list (expected empty)
    int n = min(*ovfc, OVF_CAP);
    for (int j = tid; j < n; j += 256) {
        float4 pay = ovf[j];
        int orow = (int)pay.z;
        #pragma unroll
        for (int r = 0; r < 5; ++r) {
            int sr = min(max(ybase + r, 0), H_IN - 1);
            if (orow != rowbase + sr) continue;
            float tn = pay.x / bm;
            int xi = (int)pay.y;
            float u0 = (tn + 1.f) * (0.5f * (float)TN);
            int k0 = (int)floorf(u0);
            float f = u0 - (float)k0;
            for (int bin = 0; bin < C_BINS; ++bin) {
                int k = k0 - 128 * bin;
                float fb = f;
                if (k >= TN) { k = TN - 1; fb = 1.f; }
                if (k < 0)   { k = 0;      fb = 0.f; }
                float t0 = table[k], t1 = table[k + 1];
                float g = fmaf(t1 - t0, fb, t0);
                atomicAdd(&sm[r * ROWF + xi * C_BINS + bin], tn * g);
            }
        }
    }
    __syncthreads();

    // bilinear resize straight out of LDS, 9 planes per block
    int PB = b * 18 + p * 9;
    for (int g = tid; g < 1280; g += 256) {
        int row = g / 160;
        int gx = g - row * 160;
        int ry = ry0 + row;
        float sy = fmaf((float)ry + 0.5f, 0.375f, -0.5f);
        int y0 = (int)floorf(sy);
        float wy = sy - (float)y0;
        const float* r0 = sm + (max(y0, 0) - ybase) * ROWF;
        const float* r1 = sm + (min(y0 + 1, H_IN - 1) - ybase) * ROWF;
        float res[C_BINS][4];
        #pragma unroll
        for (int q = 0; q < 4; ++q) {
            int ox = gx * 4 + q;
            float sx = fmaf((float)ox + 0.5f, 0.375f, -0.5f);
            int x0 = (int)floorf(sx);
            float wx = sx - (float)x0;
            int x1 = min(x0 + 1, W_IN - 1);
            x0 = max(x0, 0);
            int o0 = x0 * C_BINS, o1 = x1 * C_BINS;
            #pragma unroll
            for (int bin = 0; bin < C_BINS; ++bin) {
                float v00 = r0[o0 + bin], v01 = r0[o1 + bin];
                float v10 = r1[o0 + bin], v11 = r1[o1 + bin];
                float top = fmaf(v01 - v00, wx, v00);
                float bot = fmaf(v11 - v10, wx, v10);
                res[bin][q] = fmaf(bot - top, wy, top);
            }
        }
        int oy = 80 + ry;
        #pragma unroll
        for (int bin = 0; bin < C_BINS; ++bin) {
            float4* dst = (float4*)(out + ((size_t)(PB + bin) * IMG + oy) * IMG);
            dst[gx] = make_float4(res[bin][0], res[bin][1], res[bin][2], res[bin][3]);
        }
    }
}

extern "C" void kernel_launch(void* const* d_in, const int* in_sizes, int n_in,
                              void* d_out, int out_size, void* d_ws, size_t ws_size,
                              hipStream_t stream) {
    const float* ev = (const float*)d_in[0];
    const float* W1 = (const float*)d_in[1];
    const float* b1 = (const float*)d_in[2];
    const float* W2 = (const float*)d_in[3];
    const float* b2 = (const float*)d_in[4];
    const float* W3 = (const float*)d_in[5];
    const float* b3 = (const float*)d_in[6];
    float* out = (float*)d_out;

    char* ws = (char*)d_ws;
    int*    bmax_i = (int*)(ws + WS_BMAX_OFF);
    int*    ovfc   = (int*)(ws + WS_OVFC_OFF);
    float*  table  = (float*)(ws + WS_TABLE_OFF);
    int*    cursor = (int*)(ws + WS_CUR_OFF);
    float2* bucket = (float2*)(ws + WS_BKT_OFF);
    float4* ovf    = (float4*)(ws + WS_OVF_OFF);

    prep_kernel<<<TN + 1, 128, 0, stream>>>(W1, b1, W2, b2, W3, b3,
                                            table, cursor, ovfc);
    place_kernel<<<(NEV + 255) / 256, 256, 0, stream>>>(ev, cursor, bucket,
                                                        bmax_i, ovfc, ovf);
    fused_kernel<<<960 + 288, 256, 0, stream>>>(bucket, cursor, bmax_i, table,
                                                ovf, ovfc, out);
}